// Round 1
// baseline (576.378 us; speedup 1.0000x reference)
//
#include <hip/hip_runtime.h>
#include <cstddef>

#define G 64
#define NPG 1024
#define NNODES 65536
#define NEDGE 1048576
#define CAP 24576              // per-graph CSR capacity (mean 16384, std ~127)
#define HSTR 20                // padded LDS row stride for h (floats); 80B rows, 16B aligned
#define ZSTR 12                // padded LDS row stride for z (floats); 48B rows, 16B aligned
#define ADJ_ELEMS 67108864ull  // 64*1024*1024
#define BM_WORDS 2097152       // 64 graphs * 1024*1024 bits / 32 = 8 MB bitmap

typedef float f32x4 __attribute__((ext_vector_type(4)));
typedef unsigned u32x4 __attribute__((ext_vector_type(4)));

// ---------------- K1: zero degree array + accumulators + edge bitmap ----------------
__global__ __launch_bounds__(1024) void k_init(int* __restrict__ deg, float* __restrict__ acc,
                                               unsigned* __restrict__ bm) {
  int i = blockIdx.x * 1024 + threadIdx.x;
  deg[i] = 0;
  if (i < 3) acc[i] = 0.0f;
  u32x4 z = {0u, 0u, 0u, 0u};
  u32x4* b4 = (u32x4*)bm;
  for (int k = i; k < BM_WORDS / 4; k += 65536) b4[k] = z;   // 8 iters, 8 MB
}

// ---------------- K2: degree histogram over dst + edge bitmap build ----------------
// bitmap is 8 MB -> L2-resident; atomicOr contention only on identical (src, dst/32) pairs.
__global__ __launch_bounds__(256) void k_deg(const int* __restrict__ ei, int* __restrict__ deg,
                                             unsigned* __restrict__ bm) {
  int stride = gridDim.x * blockDim.x;
  for (int e = blockIdx.x * blockDim.x + threadIdx.x; e < NEDGE; e += stride) {
    int src = ei[e], dst = ei[NEDGE + e];
    atomicAdd(&deg[dst], 1);
    int gg = src >> 10, ls = src & (NPG - 1), ld = dst & (NPG - 1);
    atomicOr(&bm[gg * 32768 + ls * 32 + (ld >> 5)], 1u << (ld & 31));
  }
}

// ---------------- K3: per-graph exclusive scan -> row_ptr, cursor ----------------
__global__ __launch_bounds__(1024) void k_scan(const int* __restrict__ deg,
                                               int* __restrict__ row_ptr,
                                               int* __restrict__ cursor) {
  __shared__ int sc[1024];
  int g = blockIdx.x, t = threadIdx.x;
  int v = deg[g * NPG + t];
  sc[t] = v;
  __syncthreads();
  for (int o = 1; o < 1024; o <<= 1) {
    int x = (t >= o) ? sc[t - o] : 0;
    __syncthreads();
    sc[t] += x;
    __syncthreads();
  }
  int start = g * CAP + (sc[t] - v);   // exclusive prefix
  row_ptr[g * 1025 + t] = start;
  cursor[g * NPG + t] = start;
  if (t == 1023) row_ptr[g * 1025 + 1024] = g * CAP + sc[1023];
}

// ---------------- K4: fill CSR column list (local src ids) ----------------
__global__ __launch_bounds__(256) void k_csr(const int* __restrict__ ei,
                                             int* __restrict__ cursor,
                                             int* __restrict__ col) {
  int stride = gridDim.x * blockDim.x;
  for (int e = blockIdx.x * blockDim.x + threadIdx.x; e < NEDGE; e += stride) {
    int dst = ei[NEDGE + e];
    int pos = atomicAdd(&cursor[dst], 1);
    col[pos] = ei[e] & (NPG - 1);
  }
}

// ---------------- K5: GIN encoder (blocks 0..63) + dense_adj writing (blocks 64+) ----------------
// dense_adj is now written in FINAL form (bit -> 1.0/0.0) from the L2-resident bitmap,
// overlapped with the 64-CU GIN phase; no scatter pass needed later.
__global__ __launch_bounds__(1024) void k_gin(
    const float* __restrict__ x, const float* __restrict__ eps,
    const int* __restrict__ row_ptr, const int* __restrict__ col,
    const float* __restrict__ W0a, const float* __restrict__ b0a,
    const float* __restrict__ W0b, const float* __restrict__ b0b,
    const float* __restrict__ Wa, const float* __restrict__ ba,
    const float* __restrict__ Wb, const float* __restrict__ bb,
    const float* __restrict__ Wm, const float* __restrict__ bm_,
    const float* __restrict__ Ws, const float* __restrict__ bs,
    const unsigned* __restrict__ ebm,
    float* __restrict__ zbuf, float* __restrict__ acc, float* __restrict__ out) {
  __shared__ float hbuf[NPG * HSTR];     // 80 KB
  __shared__ float red[16];

  if (blockIdx.x >= G) {
    // write final dense_adj from bitmap (overlaps with GIN work)
    f32x4* dz = (f32x4*)(out + 2 + ADJ_ELEMS);
    size_t i = (size_t)(blockIdx.x - G) * 1024 + threadIdx.x;
    size_t stride = (size_t)(gridDim.x - G) * 1024;
    for (; i < ADJ_ELEMS / 4; i += stride) {
      unsigned w = ebm[i >> 3];
      int sh = ((int)i & 7) << 2;
      f32x4 v;
      v.x = ((w >> (sh + 0)) & 1) ? 1.f : 0.f;
      v.y = ((w >> (sh + 1)) & 1) ? 1.f : 0.f;
      v.z = ((w >> (sh + 2)) & 1) ? 1.f : 0.f;
      v.w = ((w >> (sh + 3)) & 1) ? 1.f : 0.f;
      __builtin_nontemporal_store(v, &dz[i]);
    }
    return;
  }

  const int g = blockIdx.x;
  const int tid = threadIdx.x;
  const int base = row_ptr[g * 1025 + tid];
  const int end  = row_ptr[g * 1025 + tid + 1];

  // load x -> hbuf (h0 = x)
  {
    const float4* xg = (const float4*)(x + (size_t)g * (NPG * 16));
    for (int idx = tid; idx < NPG * 4; idx += 1024) {
      float4 v = xg[idx];
      *(float4*)(hbuf + (idx >> 2) * HSTR + (idx & 3) * 4) = v;
    }
  }
  __syncthreads();

  for (int l = 0; l < 10; ++l) {
    const float* Aw = (l == 0) ? W0a : Wa + (l - 1) * 256;
    const float* Ab = (l == 0) ? b0a : ba + (l - 1) * 16;
    const float* Bw = (l == 0) ? W0b : Wb + (l - 1) * 256;
    const float* Bb = (l == 0) ? b0b : bb + (l - 1) * 16;

    // gather: agg = h[dst] + sum_{src in N(dst)} h[src], in registers
    float4 a0 = *(const float4*)(hbuf + tid * HSTR + 0);
    float4 a1 = *(const float4*)(hbuf + tid * HSTR + 4);
    float4 a2 = *(const float4*)(hbuf + tid * HSTR + 8);
    float4 a3 = *(const float4*)(hbuf + tid * HSTR + 12);
    for (int k = base; k < end; ++k) {
      int ls = col[k];
      const float* hp = hbuf + ls * HSTR;
      float4 v0 = *(const float4*)(hp + 0);
      float4 v1 = *(const float4*)(hp + 4);
      float4 v2 = *(const float4*)(hp + 8);
      float4 v3 = *(const float4*)(hp + 12);
      a0.x += v0.x; a0.y += v0.y; a0.z += v0.z; a0.w += v0.w;
      a1.x += v1.x; a1.y += v1.y; a1.z += v1.z; a1.w += v1.w;
      a2.x += v2.x; a2.y += v2.y; a2.z += v2.z; a2.w += v2.w;
      a3.x += v3.x; a3.y += v3.y; a3.z += v3.z; a3.w += v3.w;
    }
    float aa[16] = {a0.x, a0.y, a0.z, a0.w, a1.x, a1.y, a1.z, a1.w,
                    a2.x, a2.y, a2.z, a2.w, a3.x, a3.y, a3.z, a3.w};

    // MLP with scalar-loaded (SGPR) weights
    float u[16], v[16];
    #pragma unroll
    for (int j = 0; j < 16; ++j) u[j] = Ab[j];
    #pragma unroll
    for (int i = 0; i < 16; ++i) {
      float ai = aa[i];
      #pragma unroll
      for (int j = 0; j < 16; ++j) u[j] += ai * Aw[i * 16 + j];
    }
    #pragma unroll
    for (int j = 0; j < 16; ++j) u[j] = fmaxf(u[j], 0.f);
    #pragma unroll
    for (int j = 0; j < 16; ++j) v[j] = Bb[j];
    #pragma unroll
    for (int i = 0; i < 16; ++i) {
      float ui = u[i];
      #pragma unroll
      for (int j = 0; j < 16; ++j) v[j] += ui * Bw[i * 16 + j];
    }
    const bool rl = (l != 9);   // relu after every conv except the last
    __syncthreads();            // all gathers of old h done before overwrite
    #pragma unroll
    for (int j4 = 0; j4 < 4; ++j4) {
      float4 w;
      w.x = rl ? fmaxf(v[j4 * 4 + 0], 0.f) : v[j4 * 4 + 0];
      w.y = rl ? fmaxf(v[j4 * 4 + 1], 0.f) : v[j4 * 4 + 1];
      w.z = rl ? fmaxf(v[j4 * 4 + 2], 0.f) : v[j4 * 4 + 2];
      w.w = rl ? fmaxf(v[j4 * 4 + 3], 0.f) : v[j4 * 4 + 3];
      *(float4*)(hbuf + tid * HSTR + j4 * 4) = w;
    }
    __syncthreads();
  }

  // ---- heads: mu, std=softplus, z = mu + std*eps, KL (weights via SGPR loads) ----
  float hv[16];
  #pragma unroll
  for (int i = 0; i < 16; ++i) hv[i] = hbuf[tid * HSTR + i];  // own row, just wrote it

  float mu[8], st[8];
  #pragma unroll
  for (int m = 0; m < 8; ++m) { mu[m] = bm_[m]; st[m] = bs[m]; }
  #pragma unroll
  for (int i = 0; i < 16; ++i) {
    float hi = hv[i];
    #pragma unroll
    for (int m = 0; m < 8; ++m) { mu[m] += hi * Wm[i * 8 + m]; st[m] += hi * Ws[i * 8 + m]; }
  }
  #pragma unroll
  for (int m = 0; m < 8; ++m) {
    float s = st[m];
    st[m] = fmaxf(s, 0.f) + log1pf(__expf(-fabsf(s)));  // stable softplus, keeps tail
  }
  int gid = g * NPG + tid;
  float4 e0 = *(const float4*)(eps + (size_t)gid * 8);
  float4 e1 = *(const float4*)(eps + (size_t)gid * 8 + 4);
  float ev[8] = {e0.x, e0.y, e0.z, e0.w, e1.x, e1.y, e1.z, e1.w};
  float zv[8];
  float klp = 0.f;
  #pragma unroll
  for (int m = 0; m < 8; ++m) {
    zv[m] = mu[m] + st[m] * ev[m];
    klp += -__logf(st[m]) + 0.5f * (st[m] * st[m] + mu[m] * mu[m]) - 0.5f;
  }
  *(float4*)(zbuf + (size_t)gid * 8) = make_float4(zv[0], zv[1], zv[2], zv[3]);
  *(float4*)(zbuf + (size_t)gid * 8 + 4) = make_float4(zv[4], zv[5], zv[6], zv[7]);

  for (int o = 32; o > 0; o >>= 1) klp += __shfl_down(klp, o, 64);
  if ((tid & 63) == 0) red[tid >> 6] = klp;
  __syncthreads();
  if (tid == 0) {
    float s = 0.f;
    for (int i = 0; i < 16; ++i) s += red[i];
    atomicAdd(&acc[2], s);
  }
}

// ---------------- K6: adj_pred + full nll via bitmap (no scatter, no correction) ----------------
// Clamp semantics of the f32 reference, via explicit cutoffs:
//  t = exp(-s); t < 2^-24  => fl(1+t)==1 => p==1.0f => log1p(-1)=-inf => -100, logp=0
//  t = inf (s < -88.7)     => p==0       => log(0) = -inf => -100 ; log1p(-0)=0
//  else: log(p) = -log(1+t), log(1-p) = -s - log(1+t)  (analytic, no cancellation)
// Edge bit d selects which term this element contributes: d ? logp : log1mp.
__global__ __launch_bounds__(256) void k_adj(const float* __restrict__ zbuf,
                                             const unsigned* __restrict__ ebm,
                                             float* __restrict__ out,
                                             float* __restrict__ acc) {
  __shared__ float zsh[NPG * ZSTR];   // 48 KB
  __shared__ float red[4];
  const int tid = threadIdx.x;
  const float T_ONE = 5.9604645e-08f;   // 2^-24
  const float T_INF = 3.0e38f;

  const int g = blockIdx.x >> 6;
  const int i0 = (blockIdx.x & 63) << 4;
  {
    const float4* zg = (const float4*)(zbuf + (size_t)g * (NPG * 8));
    for (int idx = tid; idx < NPG * 2; idx += 256) {
      float4 v = zg[idx];
      *(float4*)(zsh + (idx >> 1) * ZSTR + (idx & 1) * 4) = v;
    }
  }
  __syncthreads();

  const int il = tid >> 4, jl = tid & 15;
  const int irow = i0 + il;
  const unsigned* bmrow = ebm + g * 32768 + irow * 32;   // 128B of bits for this row
  float4 zi0 = *(const float4*)(zsh + irow * ZSTR + 0);
  float4 zi1 = *(const float4*)(zsh + irow * ZSTR + 4);
  float accl = 0.f;
  float* orow = out + 2 + (size_t)g * (NPG * NPG) + (size_t)irow * NPG;
  unsigned w = 0;
  for (int jj = 0; jj < 64; ++jj) {
    int j = jl + (jj << 4);
    if (!(jj & 1)) w = bmrow[jj >> 1];            // uniform across the 16 jl lanes
    int d = (w >> (jl + ((jj & 1) << 4))) & 1;
    float4 zr0 = *(const float4*)(zsh + j * ZSTR + 0);
    float4 zr1 = *(const float4*)(zsh + j * ZSTR + 4);
    float s = zi0.x * zr0.x + zi0.y * zr0.y + zi0.z * zr0.z + zi0.w * zr0.w
            + zi1.x * zr1.x + zi1.y * zr1.y + zi1.z * zr1.z + zi1.w * zr1.w;
    float t = __expf(-s);
    float p = __builtin_amdgcn_rcpf(1.f + t);
    __builtin_nontemporal_store(p, &orow[j]);
    float lp, lm;
    if (t > T_INF)      { lp = -100.f; lm = 0.f; }
    else if (t < T_ONE) { lp = 0.f;    lm = -100.f; }
    else { float q = __logf(1.f + t); lp = -q; lm = -s - q; }
    accl += d ? lp : lm;
  }
  for (int o = 32; o > 0; o >>= 1) accl += __shfl_down(accl, o, 64);
  if ((tid & 63) == 0) red[tid >> 6] = accl;
  __syncthreads();
  if (tid == 0) atomicAdd(&acc[0], red[0] + red[1] + red[2] + red[3]);
}

// ---------------- K7: finalize scalars ----------------
__global__ void k_fin(const float* __restrict__ acc, float* __restrict__ out) {
  if (threadIdx.x == 0 && blockIdx.x == 0) {
    out[0] = -(acc[0] + acc[1]);   // nll (acc[1] stays 0, kept for layout stability)
    out[1] = acc[2];               // kl
  }
}

extern "C" void kernel_launch(void* const* d_in, const int* in_sizes, int n_in,
                              void* d_out, int out_size, void* d_ws, size_t ws_size,
                              hipStream_t stream) {
  const float* x   = (const float*)d_in[0];
  const float* eps = (const float*)d_in[1];
  const int*   ei  = (const int*)d_in[2];
  // d_in[3] = num_graphs (64, hardcoded)
  const float* W0a = (const float*)d_in[4];
  const float* b0a = (const float*)d_in[5];
  const float* W0b = (const float*)d_in[6];
  const float* b0b = (const float*)d_in[7];
  const float* Wa  = (const float*)d_in[8];
  const float* ba  = (const float*)d_in[9];
  const float* Wb  = (const float*)d_in[10];
  const float* bb  = (const float*)d_in[11];
  const float* Wm  = (const float*)d_in[12];
  const float* bm  = (const float*)d_in[13];
  const float* Ws  = (const float*)d_in[14];
  const float* bs  = (const float*)d_in[15];
  float* out = (float*)d_out;

  // ws layout (ints then floats then bitmap; every segment 16B-aligned)
  int* deg       = (int*)d_ws;                  // 65536
  int* row_ptr   = deg + NNODES;                // 64*1025 = 65600
  int* cursor    = row_ptr + G * 1025;          // 65536
  int* col       = cursor + NNODES;             // 64*CAP = 1572864
  float* zbuf    = (float*)(col + G * CAP);     // 65536*8
  unsigned* ebm  = (unsigned*)(zbuf + (size_t)NNODES * 8);  // 2M words = 8 MB
  float* acc     = (float*)(ebm + BM_WORDS);    // 3 floats: S1(nll), S2(unused), KL

  k_init<<<64, 1024, 0, stream>>>(deg, acc, ebm);
  k_deg<<<1024, 256, 0, stream>>>(ei, deg, ebm);
  k_scan<<<G, 1024, 0, stream>>>(deg, row_ptr, cursor);
  k_csr<<<1024, 256, 0, stream>>>(ei, cursor, col);
  k_gin<<<256, 1024, 0, stream>>>(x, eps, row_ptr, col,
                                  W0a, b0a, W0b, b0b, Wa, ba, Wb, bb,
                                  Wm, bm, Ws, bs, ebm, zbuf, acc, out);
  k_adj<<<4096, 256, 0, stream>>>(zbuf, ebm, out, acc);
  k_fin<<<1, 64, 0, stream>>>(acc, out);
}